// Round 18
// baseline (58.514 us; speedup 1.0000x reference)
//
#include <hip/hip_runtime.h>
#include <hip/hip_bf16.h>

#define NROWS 16384   // B*S
#define KD    2048    // D
#define NE    16      // experts
#define ROWS_PER_BLK 32
#define NT    32      // K tiles of 64 floats (full K per wave, no K-split)

// v18 = v17 inner structure at 2 blocks/CU for cross-block latency hiding.
//  - block = 256 thr / 4 waves / 32 rows; grid 512 = 2 blocks/CU
//  - wave w = expert quartet eq; lane = (rgrp=lane>>3 -> 4 rows, seg=lane&7)
//  - acc = 4 rows x 4 experts x 2 mats = 32 floats (the no-spill budget)
//  - W tile [32 rows][64] dbuf in LDS (16 KB), 2 global_load_lds per thread
//  - epilogue: seg-butterfly -> slab[32][33] -> per-row softplus/top2/softmax
// Output FLOAT32: [262144 probs][32768 ids-as-floats].

__device__ __forceinline__ void gload_lds16(const float* g, float* l) {
    __builtin_amdgcn_global_load_lds(
        (const __attribute__((address_space(1))) void*)g,
        (__attribute__((address_space(3))) void*)l,
        16, 0, 0);
}

__global__ __launch_bounds__(256)
void noisy_router_kernel(const float* __restrict__ x,
                         const float* __restrict__ noise,
                         const float* __restrict__ Wfc,
                         const float* __restrict__ bfc,
                         const float* __restrict__ Wns,
                         const float* __restrict__ bns,
                         float* __restrict__ out)
{
    __shared__ float lds[4096];    // 16 KB: wt0[32*64] + wt1[32*64]; slab reuse

    const int tid  = threadIdx.x;
    const int lane = tid & 63;
    const int eq   = tid >> 6;     // wave = expert quartet 0..3
    const int seg  = lane & 7;
    const int rgrp = lane >> 3;

    const int rowbase = blockIdx.x * ROWS_PER_BLK + rgrp * 4;

    float* const wt0 = lds;
    float* const wt1 = lds + 2048;

    // staging (2 instrs/thread): instr0 -> Wfc expert (tid>>4) into LDS rows 0..15,
    // instr1 -> Wns likewise into rows 16..31; col=(tid&15)*4.
    // dest byte = instr*4096 + tid*16  (wave-uniform base + lane*16: legal form)
    const float* wsrc0 = Wfc + (size_t)(tid >> 4) * KD + (tid & 15) * 4;
    const float* wsrc1 = Wns + (size_t)(tid >> 4) * KD + (tid & 15) * 4;
    const int sdst0 = (tid >> 4) * 64 + (tid & 15) * 4;
    const int sdst1 = sdst0 + 1024;

    const float* xb = x + (size_t)rowbase * KD + seg * 8;

    float accA[4][4], accB[4][4];          // [row j][expert e] -- 32 floats
    #pragma unroll
    for (int j = 0; j < 4; ++j)
        #pragma unroll
        for (int e = 0; e < 4; ++e) { accA[j][e] = 0.f; accB[j][e] = 0.f; }

#define STAGE(DST, T) { gload_lds16(wsrc0 + (T) * 64, (DST) + sdst0); \
                        gload_lds16(wsrc1 + (T) * 64, (DST) + sdst1); }

#define BODY(WT, T) { \
    float4 xv0_0, xv0_1, xv1_0, xv1_1, xv2_0, xv2_1, xv3_0, xv3_1;      \
    xv0_0 = *(const float4*)(xb + 0 * KD + (T) * 64);                   \
    xv0_1 = *(const float4*)(xb + 0 * KD + (T) * 64 + 4);               \
    xv1_0 = *(const float4*)(xb + 1 * KD + (T) * 64);                   \
    xv1_1 = *(const float4*)(xb + 1 * KD + (T) * 64 + 4);               \
    xv2_0 = *(const float4*)(xb + 2 * KD + (T) * 64);                   \
    xv2_1 = *(const float4*)(xb + 2 * KD + (T) * 64 + 4);               \
    xv3_0 = *(const float4*)(xb + 3 * KD + (T) * 64);                   \
    xv3_1 = *(const float4*)(xb + 3 * KD + (T) * 64 + 4);               \
    if ((T) + 1 < NT) { STAGE(((T) & 1) ? wt0 : wt1, (T) + 1) }         \
    const float* wpA = (WT) + eq * 256 + seg * 8;                       \
    const float* wpB = wpA + 1024;                                      \
    _Pragma("unroll")                                                   \
    for (int e = 0; e < 4; ++e) {                                       \
        const float4 a0 = *(const float4*)(wpA + e * 64);               \
        const float4 a1 = *(const float4*)(wpA + e * 64 + 4);           \
        const float4 b0 = *(const float4*)(wpB + e * 64);               \
        const float4 b1 = *(const float4*)(wpB + e * 64 + 4);           \
        accA[0][e] = fmaf(xv0_0.x, a0.x, accA[0][e]);                   \
        accA[0][e] = fmaf(xv0_0.y, a0.y, accA[0][e]);                   \
        accA[0][e] = fmaf(xv0_0.z, a0.z, accA[0][e]);                   \
        accA[0][e] = fmaf(xv0_0.w, a0.w, accA[0][e]);                   \
        accA[0][e] = fmaf(xv0_1.x, a1.x, accA[0][e]);                   \
        accA[0][e] = fmaf(xv0_1.y, a1.y, accA[0][e]);                   \
        accA[0][e] = fmaf(xv0_1.z, a1.z, accA[0][e]);                   \
        accA[0][e] = fmaf(xv0_1.w, a1.w, accA[0][e]);                   \
        accB[0][e] = fmaf(xv0_0.x, b0.x, accB[0][e]);                   \
        accB[0][e] = fmaf(xv0_0.y, b0.y, accB[0][e]);                   \
        accB[0][e] = fmaf(xv0_0.z, b0.z, accB[0][e]);                   \
        accB[0][e] = fmaf(xv0_0.w, b0.w, accB[0][e]);                   \
        accB[0][e] = fmaf(xv0_1.x, b1.x, accB[0][e]);                   \
        accB[0][e] = fmaf(xv0_1.y, b1.y, accB[0][e]);                   \
        accB[0][e] = fmaf(xv0_1.z, b1.z, accB[0][e]);                   \
        accB[0][e] = fmaf(xv0_1.w, b1.w, accB[0][e]);                   \
        accA[1][e] = fmaf(xv1_0.x, a0.x, accA[1][e]);                   \
        accA[1][e] = fmaf(xv1_0.y, a0.y, accA[1][e]);                   \
        accA[1][e] = fmaf(xv1_0.z, a0.z, accA[1][e]);                   \
        accA[1][e] = fmaf(xv1_0.w, a0.w, accA[1][e]);                   \
        accA[1][e] = fmaf(xv1_1.x, a1.x, accA[1][e]);                   \
        accA[1][e] = fmaf(xv1_1.y, a1.y, accA[1][e]);                   \
        accA[1][e] = fmaf(xv1_1.z, a1.z, accA[1][e]);                   \
        accA[1][e] = fmaf(xv1_1.w, a1.w, accA[1][e]);                   \
        accB[1][e] = fmaf(xv1_0.x, b0.x, accB[1][e]);                   \
        accB[1][e] = fmaf(xv1_0.y, b0.y, accB[1][e]);                   \
        accB[1][e] = fmaf(xv1_0.z, b0.z, accB[1][e]);                   \
        accB[1][e] = fmaf(xv1_0.w, b0.w, accB[1][e]);                   \
        accB[1][e] = fmaf(xv1_1.x, b1.x, accB[1][e]);                   \
        accB[1][e] = fmaf(xv1_1.y, b1.y, accB[1][e]);                   \
        accB[1][e] = fmaf(xv1_1.z, b1.z, accB[1][e]);                   \
        accB[1][e] = fmaf(xv1_1.w, b1.w, accB[1][e]);                   \
        accA[2][e] = fmaf(xv2_0.x, a0.x, accA[2][e]);                   \
        accA[2][e] = fmaf(xv2_0.y, a0.y, accA[2][e]);                   \
        accA[2][e] = fmaf(xv2_0.z, a0.z, accA[2][e]);                   \
        accA[2][e] = fmaf(xv2_0.w, a0.w, accA[2][e]);                   \
        accA[2][e] = fmaf(xv2_1.x, a1.x, accA[2][e]);                   \
        accA[2][e] = fmaf(xv2_1.y, a1.y, accA[2][e]);                   \
        accA[2][e] = fmaf(xv2_1.z, a1.z, accA[2][e]);                   \
        accA[2][e] = fmaf(xv2_1.w, a1.w, accA[2][e]);                   \
        accB[2][e] = fmaf(xv2_0.x, b0.x, accB[2][e]);                   \
        accB[2][e] = fmaf(xv2_0.y, b0.y, accB[2][e]);                   \
        accB[2][e] = fmaf(xv2_0.z, b0.z, accB[2][e]);                   \
        accB[2][e] = fmaf(xv2_0.w, b0.w, accB[2][e]);                   \
        accB[2][e] = fmaf(xv2_1.x, b1.x, accB[2][e]);                   \
        accB[2][e] = fmaf(xv2_1.y, b1.y, accB[2][e]);                   \
        accB[2][e] = fmaf(xv2_1.z, b1.z, accB[2][e]);                   \
        accB[2][e] = fmaf(xv2_1.w, b1.w, accB[2][e]);                   \
        accA[3][e] = fmaf(xv3_0.x, a0.x, accA[3][e]);                   \
        accA[3][e] = fmaf(xv3_0.y, a0.y, accA[3][e]);                   \
        accA[3][e] = fmaf(xv3_0.z, a0.z, accA[3][e]);                   \
        accA[3][e] = fmaf(xv3_0.w, a0.w, accA[3][e]);                   \
        accA[3][e] = fmaf(xv3_1.x, a1.x, accA[3][e]);                   \
        accA[3][e] = fmaf(xv3_1.y, a1.y, accA[3][e]);                   \
        accA[3][e] = fmaf(xv3_1.z, a1.z, accA[3][e]);                   \
        accA[3][e] = fmaf(xv3_1.w, a1.w, accA[3][e]);                   \
        accB[3][e] = fmaf(xv3_0.x, b0.x, accB[3][e]);                   \
        accB[3][e] = fmaf(xv3_0.y, b0.y, accB[3][e]);                   \
        accB[3][e] = fmaf(xv3_0.z, b0.z, accB[3][e]);                   \
        accB[3][e] = fmaf(xv3_0.w, b0.w, accB[3][e]);                   \
        accB[3][e] = fmaf(xv3_1.x, b1.x, accB[3][e]);                   \
        accB[3][e] = fmaf(xv3_1.y, b1.y, accB[3][e]);                   \
        accB[3][e] = fmaf(xv3_1.z, b1.z, accB[3][e]);                   \
        accB[3][e] = fmaf(xv3_1.w, b1.w, accB[3][e]);                   \
    } }

    // prologue
    STAGE(wt0, 0)

    #pragma unroll 1
    for (int tp = 0; tp < NT; tp += 2) {
        __syncthreads();               // stage(tp) done (vmcnt drained at barrier)
        BODY(wt0, tp)                  // x-loads, stage(tp+1) issue, FMAs
        __syncthreads();               // stage(tp+1) done
        BODY(wt1, tp + 1)
    }
#undef STAGE
#undef BODY

    // ---- butterfly over the 8 k-segs (masks 1,2,4 stay within seg-group) ----
    #pragma unroll
    for (int j = 0; j < 4; ++j)
        #pragma unroll
        for (int e = 0; e < 4; ++e) {
            float a = accA[j][e], b = accB[j][e];
            a += __shfl_xor(a, 1); a += __shfl_xor(a, 2); a += __shfl_xor(a, 4);
            b += __shfl_xor(b, 1); b += __shfl_xor(b, 2); b += __shfl_xor(b, 4);
            accA[j][e] = a; accB[j][e] = b;
        }

    __syncthreads();                  // all tile reads done; lds reusable as slab
    float* const slab = lds;          // [32 rows][stride 33]

    if (seg == 0) {                   // each wave owns complete (row, e-quartet) outs
        #pragma unroll
        for (int j = 0; j < 4; ++j) {
            float* dst = slab + (rgrp * 4 + j) * 33 + eq * 4;
            #pragma unroll
            for (int e = 0; e < 4; ++e) { dst[e] = accA[j][e]; dst[16 + e] = accB[j][e]; }
        }
    }
    __syncthreads();

    // ---- per-row epilogue: softplus noise, top-2, sparse softmax ----
    if (tid < ROWS_PER_BLK) {
        const int r = tid;
        const float* rowp = slab + r * 33;
        const size_t grow = (size_t)blockIdx.x * ROWS_PER_BLK + r;
        const float* nzp = noise + grow * NE;

        float m1 = -1e30f, m2 = -1e30f;
        int i1 = 0, i2 = 0;
        #pragma unroll
        for (int j = 0; j < NE; ++j) {
            const float z  = rowp[16 + j] + bns[j];
            const float sp = fmaxf(z, 0.f) + log1pf(expf(-fabsf(z)));  // jax softplus
            const float v  = fmaf(nzp[j], sp, rowp[j] + bfc[j]);
            if (v > m1)      { m2 = m1; i2 = i1; m1 = v; i1 = j; }     // ties -> lower idx
            else if (v > m2) { m2 = v;  i2 = j; }
        }
        const float e2  = expf(m2 - m1);
        const float inv = 1.f / (1.f + e2);

        float* po = out + grow * NE;
        #pragma unroll
        for (int j = 0; j < NE; ++j) {
            po[j] = (j == i1) ? inv : ((j == i2) ? e2 * inv : 0.f);
        }
        float* pi = out + (size_t)NROWS * NE + grow * 2;
        pi[0] = (float)i1;
        pi[1] = (float)i2;
    }
}

extern "C" void kernel_launch(void* const* d_in, const int* in_sizes, int n_in,
                              void* d_out, int out_size, void* d_ws, size_t ws_size,
                              hipStream_t stream)
{
    const float* x     = (const float*)d_in[0];
    const float* noise = (const float*)d_in[1];
    const float* Wfc   = (const float*)d_in[2];
    const float* bfc   = (const float*)d_in[3];
    const float* Wns   = (const float*)d_in[4];
    const float* bns   = (const float*)d_in[5];
    float* out = (float*)d_out;

    noisy_router_kernel<<<NROWS / ROWS_PER_BLK, 256, 0, stream>>>(
        x, noise, Wfc, bfc, Wns, bns, out);
}